// Round 9
// baseline (563.794 us; speedup 1.0000x reference)
//
#include <hip/hip_runtime.h>
#include <math.h>

// Problem constants
constexpr int Bn = 2, Ln = 128, Dn = 256, Hn = 256;

// log(expm1(0.01))
#define LR_SHIFT (-4.6001660040607144f)

// Workspace offsets (floats)
constexpr int OFF_Q      = 0;        // [B,L,D]
constexpr int OFF_K      = 65536;    // [B,L,D]
constexpr int OFF_V      = 131072;   // [B,L,D]
constexpr int OFF_X2     = 196608;   // [B,L,H]
constexpr int OFF_GZ1    = 262144;   // [B,L,H]  final gZ1
constexpr int OFF_GZ2    = 327680;   // [B,L,D]
constexpr int OFF_XQ     = 393216;   // [B,L,H]
constexpr int OFF_KT     = 458752;   // [B,256,128]
constexpr int OFF_A      = 524288;   // [B,L,L]
constexpr int OFF_W1T    = 557056;   // [B,D,H]
constexpr int OFF_W2T    = 688128;   // [B,H,D]
constexpr int OFF_MW1T   = 819200;   // [B,D,H]
constexpr int OFF_MW2T   = 950272;   // [B,H,D]
constexpr int OFF_LR     = 1081344;  // [B,L]
constexpr int OFF_PM     = 1081600;  // [B,L]
constexpr int OFF_PD     = 1081856;  // [B,L]
constexpr int OFF_MOMCUM = 1082112;  // [B,L]
constexpr int OFF_WDCUM  = 1082368;  // [B,L]
constexpr int OFF_C      = 1082624;  // [B,L]
constexpr int OFF_X2T    = 1083392;  // [B,256,128]
constexpr int OFF_U1     = 1148928;  // [B*L,256]  Q@W1T + b1
constexpr int OFF_V1     = 1214464;  // [B*L,256]  Q@mW1T + mb1
constexpr int OFF_U2     = 1280000;  // [B*L,256]  XQ@W2T + b2
constexpr int OFF_V2     = 1345536;  // [B*L,256]  XQ@mW2T + mb2
constexpr int OFF_P1     = 1411072;  // [B,128,128]  score1, then score2 (phases ordered)
// total 1443840 floats ~= 5.8 MB

// Output offsets (floats)
constexpr int OUT_ZQ2  = 0;
constexpr int OUT_W1P  = 65536;
constexpr int OUT_B1P  = 196608;
constexpr int OUT_W2P  = 197120;
constexpr int OUT_B2P  = 328192;
constexpr int OUT_MGW1 = 328704;
constexpr int OUT_MGB1 = 459776;
constexpr int OUT_MGW2 = 460288;
constexpr int OUT_MGB2 = 591360;

struct KParams {
    const float *x;
    const float *Wq, *bq, *Wk, *bk, *Wv, *bv;
    const float *Wlr, *blr, *Wm, *bm, *Wd, *bd;
    const float *W1, *b1, *W2, *b2, *mW1, *mb1, *mW2, *mb2;
    float *out, *ws;
};

__device__ __forceinline__ float softplus_f(float z) {
    return fmaxf(z, 0.0f) + log1pf(expf(-fabsf(z)));
}
__device__ __forceinline__ float4 fma4(float s, const float4 w, float4 a) {
    a.x += s * w.x; a.y += s * w.y; a.z += s * w.z; a.w += s * w.w; return a;
}
__device__ __forceinline__ float silu_f(float z) {
    return z / (1.0f + expf(-z));
}
__device__ __forceinline__ float dsilu_mul(float a, float z) {
    float sg = 1.0f / (1.0f + expf(-z));
    return a * (sg * (1.0f + z * (1.0f - sg)));
}

// stage 8 rows of 256 floats into LDS [8][260]
__device__ __forceinline__ void stage8(const float* __restrict__ src,
                                       float (*xs)[260], int t) {
#pragma unroll
    for (int i = 0; i < 2; ++i) {
        int e = t + i * 256; int tok = e >> 6, kq = e & 63;
        *(float4*)&xs[tok][kq * 4] = *(const float4*)(src + tok * 256 + kq * 4);
    }
}

// acc = sum_k xs[tok][k] * W[k*ldw + 0..3], k=0..255, 16-deep batches (R6 best)
__device__ __forceinline__ float4 dot256(const float (*xs)[260], int tok,
                                         const float* __restrict__ Wc, int ldw) {
    float4 a = {0, 0, 0, 0};
    for (int k0 = 0; k0 < 256; k0 += 16) {
        float4 wb[16];
#pragma unroll
        for (int kk = 0; kk < 16; ++kk)
            wb[kk] = *(const float4*)(Wc + (k0 + kk) * ldw);
#pragma unroll
        for (int kk = 0; kk < 16; ++kk)
            a = fma4(xs[tok][k0 + kk], wb[kk], a);
    }
    return a;
}

// last-token weight-output tile (16x16), fam: 0 -> W1p/mgW1, 1 -> W2p/mgW2
__device__ __forceinline__ void lastw_unit(const KParams& p, float* smem, int t,
                                           int b, int fam, int i0, int j0) {
    const float* ws = p.ws;
    float* wa = smem;
    float* wm = smem + 128;
    float (*LA)[16] = (float (*)[16])(smem + 256);
    float (*LM)[16] = (float (*)[16])(smem + 256 + 2048);
    float (*R)[16]  = (float (*)[16])(smem + 256 + 4096);
    const float* lr = ws + OFF_LR + b * Ln;
    const float* Pm = ws + OFF_PM + b * Ln;
    const float* Arow = ws + OFF_A + (b * Ln + Ln - 1) * Ln;
    if (t < 128) {
        wa[t] = Arow[t] * lr[t];
        wm[t] = expf(Pm[Ln - 1] - Pm[t]) * lr[t];
    }
    const float* left  = ws + (fam == 0 ? OFF_GZ1 : OFF_GZ2) + b * Ln * 256;
    const float* right = ws + (fam == 0 ? OFF_K   : OFF_X2 ) + b * Ln * 256;
    __syncthreads();
#pragma unroll
    for (int i = 0; i < 2; ++i) {
        int e = t + i * 256;
        int m = e >> 2, iq = (e & 3) * 4;
        float4 lv = *(const float4*)(left + m * 256 + i0 + iq);
        float4 rv = *(const float4*)(right + m * 256 + j0 + iq);
        float wam = wa[m], wmm = wm[m];
        LA[m][iq + 0] = wam * lv.x; LA[m][iq + 1] = wam * lv.y;
        LA[m][iq + 2] = wam * lv.z; LA[m][iq + 3] = wam * lv.w;
        LM[m][iq + 0] = wmm * lv.x; LM[m][iq + 1] = wmm * lv.y;
        LM[m][iq + 2] = wmm * lv.z; LM[m][iq + 3] = wmm * lv.w;
        R[m][iq + 0] = rv.x; R[m][iq + 1] = rv.y;
        R[m][iq + 2] = rv.z; R[m][iq + 3] = rv.w;
    }
    __syncthreads();
    int tx = t & 15, ty = t >> 4;
    float accA = 0.0f, accM = 0.0f;
#pragma unroll 4
    for (int m = 0; m < 128; ++m) {
        accA += LA[m][ty] * R[m][tx];
        accM += LM[m][ty] * R[m][tx];
    }
    float c_last  = ws[OFF_C + b * Ln + Ln - 1];
    float wd_last = ws[OFF_WDCUM + b * Ln + Ln - 1];
    float mc_last = ws[OFF_MOMCUM + b * Ln + Ln - 1];
    int i = i0 + ty, j = j0 + tx;
    const float* base1 = (fam == 0 ? p.W1 : p.W2) + b * 65536;
    const float* basem = (fam == 0 ? p.mW1 : p.mW2) + b * 65536;
    float b1v = base1[i * 256 + j], bmv = basem[i * 256 + j];
    int op = (fam == 0 ? OUT_W1P : OUT_W2P) + (b * 256 + i) * 256 + j;
    int om = (fam == 0 ? OUT_MGW1 : OUT_MGW2) + (b * 256 + i) * 256 + j;
    p.out[op] = accA - c_last * bmv + wd_last * b1v;
    p.out[om] = accM - mc_last * bmv;
}

// score tile: 8 l-rows x 128 m (src rows from global, P to global)
__device__ __forceinline__ void score_unit(const KParams& p, float* smem, int t,
                                           int b, int l0, int srcoff, int btoff,
                                           int poff) {
    const float* ws = p.ws;
    float (*qs)[260] = (float (*)[260])smem;
    stage8(ws + srcoff + (b * 128 + l0) * 256, qs, t);
    __syncthreads();
    int tok = t >> 5, mq = t & 31, m0 = 4 * mq;
    int l = l0 + tok;
    float4 s = dot256(qs, tok, ws + btoff + b * 32768 + m0, 128);
    float4 A4 = *(const float4*)(ws + OFF_A + (b * 128 + l) * 128 + m0);
    float4 L4 = *(const float4*)(ws + OFF_LR + b * 128 + m0);
    float4 pv;
    pv.x = (m0 + 0 <= l) ? A4.x * L4.x * (1.0f + s.x) : 0.0f;
    pv.y = (m0 + 1 <= l) ? A4.y * L4.y * (1.0f + s.y) : 0.0f;
    pv.z = (m0 + 2 <= l) ? A4.z * L4.z * (1.0f + s.z) : 0.0f;
    pv.w = (m0 + 3 <= l) ? A4.w * L4.w * (1.0f + s.w) : 0.0f;
    *(float4*)(p.ws + poff + b * 16384 + l * 128 + m0) = pv;
}

// P@G contraction for one token/col-quad: 16-deep main + 8-deep tail
__device__ __forceinline__ float4 pg_dot(const float* __restrict__ G,
                                         const float* __restrict__ prow,
                                         int mmax) {
    float4 acc = {0, 0, 0, 0};
    int m0 = 0;
    for (; m0 + 16 <= mmax; m0 += 16) {
        float4 gb[16];
#pragma unroll
        for (int kk = 0; kk < 16; ++kk)
            gb[kk] = *(const float4*)(G + (m0 + kk) * 256);
#pragma unroll
        for (int kk = 0; kk < 16; ++kk)
            acc = fma4(prow[m0 + kk], gb[kk], acc);
    }
    for (; m0 < mmax; m0 += 8) {
        float4 gb[8];
#pragma unroll
        for (int kk = 0; kk < 8; ++kk)
            gb[kk] = *(const float4*)(G + (m0 + kk) * 256);
#pragma unroll
        for (int kk = 0; kk < 8; ++kk)
            acc = fma4(prow[m0 + kk], gb[kk], acc);
    }
    return acc;
}

// combine tile: out = P@G - cl*V + wd*U (optionally silu) for 8 tok x 128 c
__device__ __forceinline__ void combine_unit(const KParams& p, float* smem, int t,
                                             int b, int l0, int c0, int poff,
                                             int goff, int uoff, int voff,
                                             int dooutsilu, float* dst) {
    const float* ws = p.ws;
    int bl0 = b * 128 + l0;
    float (*ps)[132] = (float (*)[132])smem;
    {
        int tok = t >> 5, mq = t & 31;
        *(float4*)&ps[tok][mq * 4] =
            *(const float4*)(ws + poff + b * 16384 + (l0 + tok) * 128 + mq * 4);
    }
    __syncthreads();
    int tok = t >> 5, q = t & 31;
    int l = l0 + tok;
    int c = c0 + 4 * q;
    float cl  = ws[OFF_C + b * 128 + l];
    float wdc = ws[OFF_WDCUM + b * 128 + l];
    float4 acc = pg_dot(ws + goff + b * 32768 + c, ps[tok], l0 + 8);
    float4 u4 = *(const float4*)(ws + uoff + (bl0 + tok) * 256 + c);
    float4 v4 = *(const float4*)(ws + voff + (bl0 + tok) * 256 + c);
    float4 o;
    o.x = acc.x - cl * v4.x + wdc * u4.x;
    o.y = acc.y - cl * v4.y + wdc * u4.y;
    o.z = acc.z - cl * v4.z + wdc * u4.z;
    o.w = acc.w - cl * v4.w + wdc * u4.w;
    if (dooutsilu) {
        o.x = silu_f(o.x); o.y = silu_f(o.y); o.z = silu_f(o.z); o.w = silu_f(o.w);
    }
    *(float4*)(dst + (bl0 + tok) * 256 + c) = o;
}

// ---------------------------------------------------------------------------
// Phase 0: fatA (2u: scalproj+scan+A per batch) + transposes (512u) +
//          QKV (192u, +KT for K) = 706
// ---------------------------------------------------------------------------
__global__ __launch_bounds__(256) void phase0_kernel(KParams p) {
    __shared__ float smem[4160];
    int u = blockIdx.x, t = threadIdx.x;
    float* ws = p.ws;
    if (u < 2) {
        // ---- scalproj (all 128 tokens) + scans + A for batch b ----
        int b = u;
        float* sm = smem;          // log_mom -> Pm
        float* sd = smem + 128;    // log_wd  -> Pd
        float* se = smem + 256;
        int wv = t >> 6, ln = t & 63;
        float4 wl = *(const float4*)(p.Wlr + ln * 4);
        float4 wm = *(const float4*)(p.Wm + ln * 4);
        float4 wd = *(const float4*)(p.Wd + ln * 4);
        for (int r = 0; r < 4; ++r) {
            float4 xr[8];
#pragma unroll
            for (int j = 0; j < 8; ++j) {
                int tok = wv * 32 + r * 8 + j;
                xr[j] = *(const float4*)(p.x + (b * 128 + tok) * 256 + ln * 4);
            }
#pragma unroll
            for (int j = 0; j < 8; ++j) {
                int tok = wv * 32 + r * 8 + j;
                float s1 = xr[j].x * wl.x + xr[j].y * wl.y + xr[j].z * wl.z + xr[j].w * wl.w;
                float s2 = xr[j].x * wm.x + xr[j].y * wm.y + xr[j].z * wm.z + xr[j].w * wm.w;
                float s3 = xr[j].x * wd.x + xr[j].y * wd.y + xr[j].z * wd.z + xr[j].w * wd.w;
#pragma unroll
                for (int off = 32; off > 0; off >>= 1) {
                    s1 += __shfl_xor(s1, off);
                    s2 += __shfl_xor(s2, off);
                    s3 += __shfl_xor(s3, off);
                }
                if (ln == 0) {
                    ws[OFF_LR + b * 128 + tok] = softplus_f(s1 + p.blr[0] + LR_SHIFT);
                    sm[tok] = -softplus_f(-(s2 + p.bm[0]));
                    sd[tok] = -softplus_f(s3 + p.bd[0]);
                }
            }
        }
        __syncthreads();
        for (int off = 1; off < 128; off <<= 1) {
            float am = 0.0f, ad = 0.0f;
            if (t < 128 && t >= off) { am = sm[t - off]; ad = sd[t - off]; }
            __syncthreads();
            if (t < 128) { sm[t] += am; sd[t] += ad; }
            __syncthreads();
        }
        if (t < 128) {
            float pm = sm[t], pd = sd[t];
            ws[OFF_PM + b * Ln + t] = pm;
            ws[OFF_PD + b * Ln + t] = pd;
            ws[OFF_MOMCUM + b * Ln + t] = expf(pm);
            ws[OFF_WDCUM + b * Ln + t]  = expf(pd);
            se[t] = expf(pm - pd);
        }
        __syncthreads();
        for (int off = 1; off < 128; off <<= 1) {
            float a = 0.0f;
            if (t < 128 && t >= off) a = se[t - off];
            __syncthreads();
            if (t < 128) se[t] += a;
            __syncthreads();
        }
        if (t < 128) ws[OFF_C + b * Ln + t] = expf(sd[t]) * se[t];
        __syncthreads();
        // A[l][m1], identical expression/order to the verified a_kernel
        for (int e = t; e < 16384; e += 256) {
            int l = e >> 7, m1 = e & 127;
            float a = 0.0f;
            if (m1 <= l) {
                float pdl = sd[l], pmm1 = sm[m1];
                float s = 0.0f;
                for (int m = m1; m <= l; ++m)
                    s += expf((pdl - sd[m]) + (sm[m] - pmm1));
                a = s;
            }
            ws[OFF_A + (b * Ln + l) * Ln + m1] = a;
        }
    } else if (u < 514) {
        int w = u - 2;
        int z = w >> 6; int mat = z >> 1; int b = z & 1;
        const float* src; float* dst;
        if (mat == 0)      { src = p.W1  + b * 65536; dst = ws + OFF_W1T  + b * 65536; }
        else if (mat == 1) { src = p.W2  + b * 65536; dst = ws + OFF_W2T  + b * 65536; }
        else if (mat == 2) { src = p.mW1 + b * 65536; dst = ws + OFF_MW1T + b * 65536; }
        else               { src = p.mW2 + b * 65536; dst = ws + OFF_MW2T + b * 65536; }
        float (*tile)[33] = (float (*)[33])smem;
        int tx = t & 31, ty = t >> 5;
        int tid = w & 63;
        int r0 = (tid >> 3) * 32, c0 = (tid & 7) * 32;
        for (int i = 0; i < 32; i += 8)
            tile[ty + i][tx] = src[(r0 + ty + i) * 256 + (c0 + tx)];
        __syncthreads();
        for (int i = 0; i < 32; i += 8)
            dst[(c0 + ty + i) * 256 + (r0 + tx)] = tile[tx][ty + i];
    } else {
        int v = u - 514; int mat = v >> 6; int r = v & 63;
        int ct = r >> 5, tt = r & 31;
        int bl0 = tt * 8, c0 = ct * 128;
        const float* W    = (mat == 0) ? p.Wq : (mat == 1) ? p.Wk : p.Wv;
        const float* bias = (mat == 0) ? p.bq : (mat == 1) ? p.bk : p.bv;
        int outoff = (mat == 0) ? OFF_Q : (mat == 1) ? OFF_K : OFF_V;
        float (*xs)[260] = (float (*)[260])smem;
        stage8(p.x + bl0 * 256, xs, t);
        __syncthreads();
        int tok = t >> 5, q = t & 31;
        int c = c0 + 4 * q;
        float4 a = dot256(xs, tok, W + c, 256);
        float4 bb = *(const float4*)(bias + c);
        a.x += bb.x; a.y += bb.y; a.z += bb.z; a.w += bb.w;
        *(float4*)(ws + outoff + (bl0 + tok) * 256 + c) = a;
        if (mat == 1) {
            int b = bl0 >> 7, l = (bl0 & 127) + tok;
            float* KT = ws + OFF_KT + b * 32768 + l;
            KT[(c + 0) * 128] = a.x; KT[(c + 1) * 128] = a.y;
            KT[(c + 2) * 128] = a.z; KT[(c + 3) * 128] = a.w;
        }
    }
}

// ---------------------------------------------------------------------------
// Phase 1: fusedMLP (32u: Z1->X2/X2T->gZ2->gZ1, LDS handoffs) +
//          U1 (64u) + V1 (64u) + score1 (32u) = 192
// ---------------------------------------------------------------------------
__global__ __launch_bounds__(256) void phase1_kernel(KParams p) {
    __shared__ float smem[8320];
    int u = blockIdx.x, t = threadIdx.x;
    float* ws = p.ws;
    if (u < 32) {
        int bl0 = u * 8, b = bl0 >> 7;
        float (*ks)[260] = (float (*)[260])smem;             // K
        float (*zs)[260] = (float (*)[260])(smem + 2080);    // Z1
        float (*as)[260] = (float (*)[260])(smem + 4160);    // X2
        float (*gs)[260] = (float (*)[260])(smem + 6240);    // gZ2
        stage8(ws + OFF_K + bl0 * 256, ks, t);
        __syncthreads();
        int tok = t >> 5, q = t & 31;
        int c = 4 * q, c2 = c + 128;
        // stage 0: Z1 = K @ W1T + b1; X2 = silu(Z1); X2T
        {
            const float* W1t = ws + OFF_W1T + b * 65536;
            float4 a0 = dot256(ks, tok, W1t + c, 256);
            float4 a1 = dot256(ks, tok, W1t + c2, 256);
            float4 bb0 = *(const float4*)(p.b1 + b * 256 + c);
            float4 bb1 = *(const float4*)(p.b1 + b * 256 + c2);
            float4 z0 = {a0.x + bb0.x, a0.y + bb0.y, a0.z + bb0.z, a0.w + bb0.w};
            float4 z1 = {a1.x + bb1.x, a1.y + bb1.y, a1.z + bb1.z, a1.w + bb1.w};
            *(float4*)&zs[tok][c]  = z0;
            *(float4*)&zs[tok][c2] = z1;
            float4 s0 = {silu_f(z0.x), silu_f(z0.y), silu_f(z0.z), silu_f(z0.w)};
            float4 s1 = {silu_f(z1.x), silu_f(z1.y), silu_f(z1.z), silu_f(z1.w)};
            *(float4*)&as[tok][c]  = s0;
            *(float4*)&as[tok][c2] = s1;
            *(float4*)(ws + OFF_X2 + (bl0 + tok) * 256 + c)  = s0;
            *(float4*)(ws + OFF_X2 + (bl0 + tok) * 256 + c2) = s1;
        }
        __syncthreads();
        // X2T transposed write (from LDS; n = t)
        {
            int l0b = bl0 & 127;
            float v1[8];
#pragma unroll
            for (int j = 0; j < 8; ++j) v1[j] = as[j][t];
            float* X2Tp = ws + OFF_X2T + b * 32768 + t * 128 + l0b;
            float4 r0 = {v1[0], v1[1], v1[2], v1[3]};
            float4 r1 = {v1[4], v1[5], v1[6], v1[7]};
            *(float4*)X2Tp = r0; *(float4*)(X2Tp + 4) = r1;
        }
        // stage 1: gZ2 = X2 @ W2T + b2 - V
        {
            const float* W2t = ws + OFF_W2T + b * 65536;
            float4 a0 = dot256(as, tok, W2t + c, 256);
            float4 a1 = dot256(as, tok, W2t + c2, 256);
            float4 bb0 = *(const float4*)(p.b2 + b * 256 + c);
            float4 bb1 = *(const float4*)(p.b2 + b * 256 + c2);
            float4 v0 = *(const float4*)(ws + OFF_V + (bl0 + tok) * 256 + c);
            float4 v1 = *(const float4*)(ws + OFF_V + (bl0 + tok) * 256 + c2);
            float4 g0 = {a0.x + bb0.x - v0.x, a0.y + bb0.y - v0.y,
                         a0.z + bb0.z - v0.z, a0.w + bb0.w - v0.w};
            float4 g1 = {a1.x + bb1.x - v1.x, a1.y + bb1.y - v1.y,
                         a1.z + bb1.z - v1.z, a1.w + bb1.w - v1.w};
            *(float4*)&gs[tok][c]  = g0;
            *(float4*)&gs[tok][c2] = g1;
            *(float4*)(ws + OFF_GZ2 + (bl0 + tok) * 256 + c)  = g0;
            *(float4*)(ws + OFF_GZ2 + (bl0 + tok) * 256 + c2) = g1;
        }
        __syncthreads();
        // stage 2: gX2 = gZ2 @ W2(native); gZ1 = gX2 * silu'(Z1)
        {
            const float* W2n = p.W2 + b * 65536;
            float4 a0 = dot256(gs, tok, W2n + c, 256);
            float4 a1 = dot256(gs, tok, W2n + c2, 256);
            float4 z0 = *(float4*)&zs[tok][c];
            float4 z1 = *(float4*)&zs[tok][c2];
            float4 g0 = {dsilu_mul(a0.x, z0.x), dsilu_mul(a0.y, z0.y),
                         dsilu_mul(a0.z, z0.z), dsilu_mul(a0.w, z0.w)};
            float4 g1 = {dsilu_mul(a1.x, z1.x), dsilu_mul(a1.y, z1.y),
                         dsilu_mul(a1.z, z1.z), dsilu_mul(a1.w, z1.w)};
            *(float4*)(ws + OFF_GZ1 + (bl0 + tok) * 256 + c)  = g0;
            *(float4*)(ws + OFF_GZ1 + (bl0 + tok) * 256 + c2) = g1;
        }
    } else if (u < 160) {
        // U1 (mat=0) / V1 (mat=1)
        int w = u - 32; int mat = w >> 6; int r = w & 63;
        int tt = r >> 1, ct = r & 1;
        int bl0 = tt * 8, c0 = ct * 128, b = bl0 >> 7;
        float (*xs)[260] = (float (*)[260])smem;
        stage8(ws + OFF_Q + bl0 * 256, xs, t);
        __syncthreads();
        int tok = t >> 5, q = t & 31;
        int c = c0 + 4 * q;
        const float* W = ws + (mat ? OFF_MW1T : OFF_W1T) + b * 65536 + c;
        const float* bias = (mat ? p.mb1 : p.b1) + b * 256 + c;
        float4 a = dot256(xs, tok, W, 256);
        float4 bb = *(const float4*)bias;
        a.x += bb.x; a.y += bb.y; a.z += bb.z; a.w += bb.w;
        *(float4*)(ws + (mat ? OFF_V1 : OFF_U1) + (bl0 + tok) * 256 + c) = a;
    } else {
        int w = u - 160; int b = w >> 4; int l0 = (w & 15) * 8;
        score_unit(p, smem, t, b, l0, OFF_Q, OFF_KT, OFF_P1);
    }
}

// ---------------------------------------------------------------------------
// Phase 2: combine1 -> XQ (64u) + lastw fam0/1 (1024u) + lastb (2u) = 1090
// ---------------------------------------------------------------------------
__global__ __launch_bounds__(256) void phase2_kernel(KParams p) {
    __shared__ float smem[6400];
    int u = blockIdx.x, t = threadIdx.x;
    float* ws = p.ws;
    if (u < 64) {
        int tt = u >> 1, ct = u & 1;
        int b = tt >> 4, l0 = (tt & 15) * 8;
        combine_unit(p, smem, t, b, l0, ct * 128, OFF_P1, OFF_GZ1,
                     OFF_U1, OFF_V1, 1, ws + OFF_XQ);
    } else if (u < 1088) {
        int w = u - 64; int z = w >> 8; int rem = w & 255;
        int b = z >> 1; int fam = z & 1;
        lastw_unit(p, smem, t, b, fam, (rem >> 4) * 16, (rem & 15) * 16);
    } else {
        int b = u - 1088;
        float* wa = smem;
        float* wm = smem + 128;
        if (t < 128) {
            wa[t] = ws[OFF_A + (b * Ln + Ln - 1) * Ln + t] * ws[OFF_LR + b * Ln + t];
            wm[t] = expf(ws[OFF_PM + b * Ln + Ln - 1] - ws[OFF_PM + b * Ln + t]) *
                    ws[OFF_LR + b * Ln + t];
        }
        __syncthreads();
        const float* gz1 = ws + OFF_GZ1 + b * Ln * 256;
        const float* gz2 = ws + OFF_GZ2 + b * Ln * 256;
        float sA1 = 0, sM1 = 0, sA2 = 0, sM2 = 0;
        for (int m0 = 0; m0 < 128; m0 += 16) {
            float g1b[16], g2b[16];
#pragma unroll
            for (int kk = 0; kk < 16; ++kk) {
                g1b[kk] = gz1[(m0 + kk) * 256 + t];
                g2b[kk] = gz2[(m0 + kk) * 256 + t];
            }
#pragma unroll
            for (int kk = 0; kk < 16; ++kk) {
                float wam = wa[m0 + kk], wmm = wm[m0 + kk];
                sA1 += wam * g1b[kk]; sM1 += wmm * g1b[kk];
                sA2 += wam * g2b[kk]; sM2 += wmm * g2b[kk];
            }
        }
        float c_last  = ws[OFF_C + b * Ln + Ln - 1];
        float wd_last = ws[OFF_WDCUM + b * Ln + Ln - 1];
        float mc_last = ws[OFF_MOMCUM + b * Ln + Ln - 1];
        p.out[OUT_B1P + b * 256 + t]  = sA1 - c_last * p.mb1[b * 256 + t] + wd_last * p.b1[b * 256 + t];
        p.out[OUT_MGB1 + b * 256 + t] = sM1 - mc_last * p.mb1[b * 256 + t];
        p.out[OUT_B2P + b * 256 + t]  = sA2 - c_last * p.mb2[b * 256 + t] + wd_last * p.b2[b * 256 + t];
        p.out[OUT_MGB2 + b * 256 + t] = sM2 - mc_last * p.mb2[b * 256 + t];
    }
}

// ---------------------------------------------------------------------------
// Phase 3: score2 (32u) + U2 (64u) + V2 (64u) = 160
// ---------------------------------------------------------------------------
__global__ __launch_bounds__(256) void phase3_kernel(KParams p) {
    __shared__ float smem[4160];
    int u = blockIdx.x, t = threadIdx.x;
    float* ws = p.ws;
    if (u < 32) {
        int b = u >> 4; int l0 = (u & 15) * 8;
        score_unit(p, smem, t, b, l0, OFF_XQ, OFF_X2T, OFF_P1);
    } else {
        int w = u - 32; int mat = w >> 6; int r = w & 63;
        int tt = r >> 1, ct = r & 1;
        int bl0 = tt * 8, c0 = ct * 128, b = bl0 >> 7;
        float (*xs)[260] = (float (*)[260])smem;
        stage8(ws + OFF_XQ + bl0 * 256, xs, t);
        __syncthreads();
        int tok = t >> 5, q = t & 31;
        int c = c0 + 4 * q;
        const float* W = ws + (mat ? OFF_MW2T : OFF_W2T) + b * 65536 + c;
        const float* bias = (mat ? p.mb2 : p.b2) + b * 256 + c;
        float4 a = dot256(xs, tok, W, 256);
        float4 bb = *(const float4*)bias;
        a.x += bb.x; a.y += bb.y; a.z += bb.z; a.w += bb.w;
        *(float4*)(ws + (mat ? OFF_V2 : OFF_U2) + (bl0 + tok) * 256 + c) = a;
    }
}

// ---------------------------------------------------------------------------
// Phase 4: combine2 -> out ZQ2 (64u)
// ---------------------------------------------------------------------------
__global__ __launch_bounds__(256) void phase4_kernel(KParams p) {
    __shared__ float smem[1056];
    int u = blockIdx.x, t = threadIdx.x;
    int tt = u >> 1, ct = u & 1;
    int b = tt >> 4, l0 = (tt & 15) * 8;
    combine_unit(p, smem, t, b, l0, ct * 128, OFF_P1, OFF_GZ2,
                 OFF_U2, OFF_V2, 0, p.out + OUT_ZQ2);
}

// ---------------------------------------------------------------------------
extern "C" void kernel_launch(void* const* d_in, const int* in_sizes, int n_in,
                              void* d_out, int out_size, void* d_ws, size_t ws_size,
                              hipStream_t stream) {
    KParams p;
    p.x   = (const float*)d_in[0];
    p.Wq  = (const float*)d_in[1];  p.bq  = (const float*)d_in[2];
    p.Wk  = (const float*)d_in[3];  p.bk  = (const float*)d_in[4];
    p.Wv  = (const float*)d_in[5];  p.bv  = (const float*)d_in[6];
    p.Wlr = (const float*)d_in[7];  p.blr = (const float*)d_in[8];
    p.Wm  = (const float*)d_in[9];  p.bm  = (const float*)d_in[10];
    p.Wd  = (const float*)d_in[11]; p.bd  = (const float*)d_in[12];
    p.W1  = (const float*)d_in[13]; p.b1  = (const float*)d_in[14];
    p.W2  = (const float*)d_in[15]; p.b2  = (const float*)d_in[16];
    p.mW1 = (const float*)d_in[17]; p.mb1 = (const float*)d_in[18];
    p.mW2 = (const float*)d_in[19]; p.mb2 = (const float*)d_in[20];
    p.out = (float*)d_out;
    p.ws  = (float*)d_ws;

    phase0_kernel<<<706, 256, 0, stream>>>(p);
    phase1_kernel<<<192, 256, 0, stream>>>(p);
    phase2_kernel<<<1090, 256, 0, stream>>>(p);
    phase3_kernel<<<160, 256, 0, stream>>>(p);
    phase4_kernel<<<64, 256, 0, stream>>>(p);
}

// Round 10
// 216.240 us; speedup vs baseline: 2.6073x; 2.6073x over previous
//
#include <hip/hip_runtime.h>
#include <math.h>

// Problem constants
constexpr int Bn = 2, Ln = 128, Dn = 256, Hn = 256;

// log(expm1(0.01))
#define LR_SHIFT (-4.6001660040607144f)

// Workspace offsets (floats)
constexpr int OFF_Q      = 0;        // [B,L,D]
constexpr int OFF_K      = 65536;    // [B,L,D]
constexpr int OFF_V      = 131072;   // [B,L,D]
constexpr int OFF_X2     = 196608;   // [B,L,H]
constexpr int OFF_GZ1    = 262144;   // [B,L,H]  final gZ1
constexpr int OFF_GZ2    = 327680;   // [B,L,D]
constexpr int OFF_XQ     = 393216;   // [B,L,H]
constexpr int OFF_KT     = 458752;   // [B,256,128]
constexpr int OFF_A      = 524288;   // [B,L,L]
constexpr int OFF_W1T    = 557056;   // [B,D,H]
constexpr int OFF_W2T    = 688128;   // [B,H,D]
constexpr int OFF_MW1T   = 819200;   // [B,D,H]
constexpr int OFF_MW2T   = 950272;   // [B,H,D]
constexpr int OFF_LR     = 1081344;  // [B,L]
constexpr int OFF_PM     = 1081600;  // [B,L]
constexpr int OFF_PD     = 1081856;  // [B,L]
constexpr int OFF_MOMCUM = 1082112;  // [B,L]
constexpr int OFF_WDCUM  = 1082368;  // [B,L]
constexpr int OFF_C      = 1082624;  // [B,L]
constexpr int OFF_LOGM   = 1082880;  // [B,L]
constexpr int OFF_LOGWD  = 1083136;  // [B,L]
constexpr int OFF_X2T    = 1083392;  // [B,256,128]
constexpr int OFF_U1     = 1148928;  // [B*L,256]  Q@W1T + b1
constexpr int OFF_V1     = 1214464;  // [B*L,256]  Q@mW1T + mb1
constexpr int OFF_U2     = 1280000;  // [B*L,256]  XQ@W2T + b2
constexpr int OFF_V2     = 1345536;  // [B*L,256]  XQ@mW2T + mb2
// total ~5.4 MB (P matrices now live in LDS only)

// Output offsets (floats)
constexpr int OUT_ZQ2  = 0;
constexpr int OUT_W1P  = 65536;
constexpr int OUT_B1P  = 196608;
constexpr int OUT_W2P  = 197120;
constexpr int OUT_B2P  = 328192;
constexpr int OUT_MGW1 = 328704;
constexpr int OUT_MGB1 = 459776;
constexpr int OUT_MGW2 = 460288;
constexpr int OUT_MGB2 = 591360;

struct KParams {
    const float *x;
    const float *Wq, *bq, *Wk, *bk, *Wv, *bv;
    const float *Wlr, *blr, *Wm, *bm, *Wd, *bd;
    const float *W1, *b1, *W2, *b2, *mW1, *mb1, *mW2, *mb2;
    float *out, *ws;
};

__device__ __forceinline__ float softplus_f(float z) {
    return fmaxf(z, 0.0f) + log1pf(expf(-fabsf(z)));
}
__device__ __forceinline__ float4 fma4(float s, const float4 w, float4 a) {
    a.x += s * w.x; a.y += s * w.y; a.z += s * w.z; a.w += s * w.w; return a;
}
__device__ __forceinline__ float silu_f(float z) {
    return z / (1.0f + expf(-z));
}
__device__ __forceinline__ float dsilu_mul(float a, float z) {
    float sg = 1.0f / (1.0f + expf(-z));
    return a * (sg * (1.0f + z * (1.0f - sg)));
}

// stage 8 rows of 256 floats into LDS [8][260]
__device__ __forceinline__ void stage8(const float* __restrict__ src,
                                       float (*xs)[260], int t) {
#pragma unroll
    for (int i = 0; i < 2; ++i) {
        int e = t + i * 256; int tok = e >> 6, kq = e & 63;
        *(float4*)&xs[tok][kq * 4] = *(const float4*)(src + tok * 256 + kq * 4);
    }
}

// acc = sum_k xs[tok][k] * W[k*ldw + 0..3], k=0..255, 16-deep batches (R6 best)
__device__ __forceinline__ float4 dot256(const float (*xs)[260], int tok,
                                         const float* __restrict__ Wc, int ldw) {
    float4 a = {0, 0, 0, 0};
    for (int k0 = 0; k0 < 256; k0 += 16) {
        float4 wb[16];
#pragma unroll
        for (int kk = 0; kk < 16; ++kk)
            wb[kk] = *(const float4*)(Wc + (k0 + kk) * ldw);
#pragma unroll
        for (int kk = 0; kk < 16; ++kk)
            a = fma4(xs[tok][k0 + kk], wb[kk], a);
    }
    return a;
}

// last-token weight-output tile (16x16), fam: 0 -> W1p/mgW1, 1 -> W2p/mgW2
__device__ __forceinline__ void lastw_unit(const KParams& p, float* smem, int t,
                                           int b, int fam, int i0, int j0) {
    const float* ws = p.ws;
    float* wa = smem;
    float* wm = smem + 128;
    float (*LA)[16] = (float (*)[16])(smem + 256);
    float (*LM)[16] = (float (*)[16])(smem + 256 + 2048);
    float (*R)[16]  = (float (*)[16])(smem + 256 + 4096);
    const float* lr = ws + OFF_LR + b * Ln;
    const float* Pm = ws + OFF_PM + b * Ln;
    const float* Arow = ws + OFF_A + (b * Ln + Ln - 1) * Ln;
    if (t < 128) {
        wa[t] = Arow[t] * lr[t];
        wm[t] = expf(Pm[Ln - 1] - Pm[t]) * lr[t];
    }
    const float* left  = ws + (fam == 0 ? OFF_GZ1 : OFF_GZ2) + b * Ln * 256;
    const float* right = ws + (fam == 0 ? OFF_K   : OFF_X2 ) + b * Ln * 256;
    __syncthreads();
#pragma unroll
    for (int i = 0; i < 2; ++i) {
        int e = t + i * 256;
        int m = e >> 2, iq = (e & 3) * 4;
        float4 lv = *(const float4*)(left + m * 256 + i0 + iq);
        float4 rv = *(const float4*)(right + m * 256 + j0 + iq);
        float wam = wa[m], wmm = wm[m];
        LA[m][iq + 0] = wam * lv.x; LA[m][iq + 1] = wam * lv.y;
        LA[m][iq + 2] = wam * lv.z; LA[m][iq + 3] = wam * lv.w;
        LM[m][iq + 0] = wmm * lv.x; LM[m][iq + 1] = wmm * lv.y;
        LM[m][iq + 2] = wmm * lv.z; LM[m][iq + 3] = wmm * lv.w;
        R[m][iq + 0] = rv.x; R[m][iq + 1] = rv.y;
        R[m][iq + 2] = rv.z; R[m][iq + 3] = rv.w;
    }
    __syncthreads();
    int tx = t & 15, ty = t >> 4;
    float accA = 0.0f, accM = 0.0f;
#pragma unroll 4
    for (int m = 0; m < 128; ++m) {
        accA += LA[m][ty] * R[m][tx];
        accM += LM[m][ty] * R[m][tx];
    }
    float c_last  = ws[OFF_C + b * Ln + Ln - 1];
    float wd_last = ws[OFF_WDCUM + b * Ln + Ln - 1];
    float mc_last = ws[OFF_MOMCUM + b * Ln + Ln - 1];
    int i = i0 + ty, j = j0 + tx;
    const float* base1 = (fam == 0 ? p.W1 : p.W2) + b * 65536;
    const float* basem = (fam == 0 ? p.mW1 : p.mW2) + b * 65536;
    float b1v = base1[i * 256 + j], bmv = basem[i * 256 + j];
    int op = (fam == 0 ? OUT_W1P : OUT_W2P) + (b * 256 + i) * 256 + j;
    int om = (fam == 0 ? OUT_MGW1 : OUT_MGW2) + (b * 256 + i) * 256 + j;
    p.out[op] = accA - c_last * bmv + wd_last * b1v;
    p.out[om] = accM - mc_last * bmv;
}

// P@G contraction for one token/col-quad: 16-deep main + 8-deep tail
__device__ __forceinline__ float4 pg_dot(const float* __restrict__ G,
                                         const float* __restrict__ prow,
                                         int mmax) {
    float4 acc = {0, 0, 0, 0};
    int m0 = 0;
    for (; m0 + 16 <= mmax; m0 += 16) {
        float4 gb[16];
#pragma unroll
        for (int kk = 0; kk < 16; ++kk)
            gb[kk] = *(const float4*)(G + (m0 + kk) * 256);
#pragma unroll
        for (int kk = 0; kk < 16; ++kk)
            acc = fma4(prow[m0 + kk], gb[kk], acc);
    }
    for (; m0 < mmax; m0 += 8) {
        float4 gb[8];
#pragma unroll
        for (int kk = 0; kk < 8; ++kk)
            gb[kk] = *(const float4*)(G + (m0 + kk) * 256);
#pragma unroll
        for (int kk = 0; kk < 8; ++kk)
            acc = fma4(prow[m0 + kk], gb[kk], acc);
    }
    return acc;
}

// fused score->combine: block = 8 tokens x one 128-col half. Scores recomputed
// in LDS (never touch global); then out = P@G - cl*V + wd*U (optional silu).
__device__ __forceinline__ void score_combine_unit(
    const KParams& p, float* smem, int t, int b, int l0, int c0,
    int srcoff, int btoff, int goff, int uoff, int voff,
    int dooutsilu, float* dst) {
    const float* ws = p.ws;
    int bl0 = b * 128 + l0;
    float (*qs)[260] = (float (*)[260])smem;
    float (*ps)[132] = (float (*)[132])(smem + 2080);
    stage8(ws + srcoff + bl0 * 256, qs, t);
    __syncthreads();
    int tok = t >> 5;
    int l = l0 + tok;
    // score: s[tok][m0..m0+3] (identical expression to verified score_unit)
    {
        int mq = t & 31, m0 = 4 * mq;
        float4 s = dot256(qs, tok, ws + btoff + b * 32768 + m0, 128);
        float4 A4 = *(const float4*)(ws + OFF_A + (b * 128 + l) * 128 + m0);
        float4 L4 = *(const float4*)(ws + OFF_LR + b * 128 + m0);
        float4 pv;
        pv.x = (m0 + 0 <= l) ? A4.x * L4.x * (1.0f + s.x) : 0.0f;
        pv.y = (m0 + 1 <= l) ? A4.y * L4.y * (1.0f + s.y) : 0.0f;
        pv.z = (m0 + 2 <= l) ? A4.z * L4.z * (1.0f + s.z) : 0.0f;
        pv.w = (m0 + 3 <= l) ? A4.w * L4.w * (1.0f + s.w) : 0.0f;
        *(float4*)&ps[tok][m0] = pv;
    }
    __syncthreads();
    // combine
    {
        int q = t & 31;
        int c = c0 + 4 * q;
        float cl  = ws[OFF_C + b * 128 + l];
        float wdc = ws[OFF_WDCUM + b * 128 + l];
        float4 acc = pg_dot(ws + goff + b * 32768 + c, ps[tok], l0 + 8);
        float4 u4 = *(const float4*)(ws + uoff + (bl0 + tok) * 256 + c);
        float4 v4 = *(const float4*)(ws + voff + (bl0 + tok) * 256 + c);
        float4 o;
        o.x = acc.x - cl * v4.x + wdc * u4.x;
        o.y = acc.y - cl * v4.y + wdc * u4.y;
        o.z = acc.z - cl * v4.z + wdc * u4.z;
        o.w = acc.w - cl * v4.w + wdc * u4.w;
        if (dooutsilu) {
            o.x = silu_f(o.x); o.y = silu_f(o.y); o.z = silu_f(o.z); o.w = silu_f(o.w);
        }
        *(float4*)(dst + (bl0 + tok) * 256 + c) = o;
    }
}

// ---------------------------------------------------------------------------
// Phase 0 (R6-verified): transposes (512u) + QKV (192u, +KT) + scalproj (64u)
// ---------------------------------------------------------------------------
__global__ __launch_bounds__(256) void phase0_kernel(KParams p) {
    __shared__ float smem[4160];
    int u = blockIdx.x, t = threadIdx.x;
    float* ws = p.ws;
    if (u < 512) {
        int z = u >> 6; int mat = z >> 1; int b = z & 1;
        const float* src; float* dst;
        if (mat == 0)      { src = p.W1  + b * 65536; dst = ws + OFF_W1T  + b * 65536; }
        else if (mat == 1) { src = p.W2  + b * 65536; dst = ws + OFF_W2T  + b * 65536; }
        else if (mat == 2) { src = p.mW1 + b * 65536; dst = ws + OFF_MW1T + b * 65536; }
        else               { src = p.mW2 + b * 65536; dst = ws + OFF_MW2T + b * 65536; }
        float (*tile)[33] = (float (*)[33])smem;
        int tx = t & 31, ty = t >> 5;
        int tid = u & 63;
        int r0 = (tid >> 3) * 32, c0 = (tid & 7) * 32;
        for (int i = 0; i < 32; i += 8)
            tile[ty + i][tx] = src[(r0 + ty + i) * 256 + (c0 + tx)];
        __syncthreads();
        for (int i = 0; i < 32; i += 8)
            dst[(c0 + ty + i) * 256 + (r0 + tx)] = tile[tx][ty + i];
    } else if (u < 704) {
        int v = u - 512; int mat = v >> 6; int r = v & 63;
        int ct = r >> 5, tt = r & 31;
        int bl0 = tt * 8, c0 = ct * 128;
        const float* W    = (mat == 0) ? p.Wq : (mat == 1) ? p.Wk : p.Wv;
        const float* bias = (mat == 0) ? p.bq : (mat == 1) ? p.bk : p.bv;
        int outoff = (mat == 0) ? OFF_Q : (mat == 1) ? OFF_K : OFF_V;
        float (*xs)[260] = (float (*)[260])smem;
        stage8(p.x + bl0 * 256, xs, t);
        __syncthreads();
        int tok = t >> 5, q = t & 31;
        int c = c0 + 4 * q;
        float4 a = dot256(xs, tok, W + c, 256);
        float4 bb = *(const float4*)(bias + c);
        a.x += bb.x; a.y += bb.y; a.z += bb.z; a.w += bb.w;
        *(float4*)(ws + outoff + (bl0 + tok) * 256 + c) = a;
        if (mat == 1) {
            int b = bl0 >> 7, l = (bl0 & 127) + tok;
            float* KT = ws + OFF_KT + b * 32768 + l;
            KT[(c + 0) * 128] = a.x; KT[(c + 1) * 128] = a.y;
            KT[(c + 2) * 128] = a.z; KT[(c + 3) * 128] = a.w;
        }
    } else {
        int blk = u - 704;
        int ln = t & 63, wv = t >> 6;
        int bl = blk * 4 + wv;
        float4 xv = *(const float4*)(p.x + bl * 256 + ln * 4);
        float4 wl = *(const float4*)(p.Wlr + ln * 4);
        float4 wm = *(const float4*)(p.Wm + ln * 4);
        float4 wd = *(const float4*)(p.Wd + ln * 4);
        float s1 = xv.x * wl.x + xv.y * wl.y + xv.z * wl.z + xv.w * wl.w;
        float s2 = xv.x * wm.x + xv.y * wm.y + xv.z * wm.z + xv.w * wm.w;
        float s3 = xv.x * wd.x + xv.y * wd.y + xv.z * wd.z + xv.w * wd.w;
#pragma unroll
        for (int off = 32; off > 0; off >>= 1) {
            s1 += __shfl_xor(s1, off);
            s2 += __shfl_xor(s2, off);
            s3 += __shfl_xor(s3, off);
        }
        if (ln == 0) {
            ws[OFF_LR + bl]    = softplus_f(s1 + p.blr[0] + LR_SHIFT);
            ws[OFF_LOGM + bl]  = -softplus_f(-(s2 + p.bm[0]));
            ws[OFF_LOGWD + bl] = -softplus_f(s3 + p.bd[0]);
        }
    }
}

// ---------------------------------------------------------------------------
// Phase 1: fusedMLP (32u, R9-verified) + U1/V1 (128u) + scan/A (256u) = 416
// ---------------------------------------------------------------------------
__global__ __launch_bounds__(256) void phase1_kernel(KParams p) {
    __shared__ float smem[8320];
    int u = blockIdx.x, t = threadIdx.x;
    float* ws = p.ws;
    if (u < 32) {
        int bl0 = u * 8, b = bl0 >> 7;
        float (*ks)[260] = (float (*)[260])smem;             // K
        float (*zs)[260] = (float (*)[260])(smem + 2080);    // Z1
        float (*as)[260] = (float (*)[260])(smem + 4160);    // X2
        float (*gs)[260] = (float (*)[260])(smem + 6240);    // gZ2
        stage8(ws + OFF_K + bl0 * 256, ks, t);
        __syncthreads();
        int tok = t >> 5, q = t & 31;
        int c = 4 * q, c2 = c + 128;
        // stage 0: Z1 = K @ W1T + b1; X2 = silu(Z1)
        {
            const float* W1t = ws + OFF_W1T + b * 65536;
            float4 a0 = dot256(ks, tok, W1t + c, 256);
            float4 a1 = dot256(ks, tok, W1t + c2, 256);
            float4 bb0 = *(const float4*)(p.b1 + b * 256 + c);
            float4 bb1 = *(const float4*)(p.b1 + b * 256 + c2);
            float4 z0 = {a0.x + bb0.x, a0.y + bb0.y, a0.z + bb0.z, a0.w + bb0.w};
            float4 z1 = {a1.x + bb1.x, a1.y + bb1.y, a1.z + bb1.z, a1.w + bb1.w};
            *(float4*)&zs[tok][c]  = z0;
            *(float4*)&zs[tok][c2] = z1;
            float4 s0 = {silu_f(z0.x), silu_f(z0.y), silu_f(z0.z), silu_f(z0.w)};
            float4 s1 = {silu_f(z1.x), silu_f(z1.y), silu_f(z1.z), silu_f(z1.w)};
            *(float4*)&as[tok][c]  = s0;
            *(float4*)&as[tok][c2] = s1;
            *(float4*)(ws + OFF_X2 + (bl0 + tok) * 256 + c)  = s0;
            *(float4*)(ws + OFF_X2 + (bl0 + tok) * 256 + c2) = s1;
        }
        __syncthreads();
        // X2T transposed write (from LDS; n = t)
        {
            int l0b = bl0 & 127;
            float v1[8];
#pragma unroll
            for (int j = 0; j < 8; ++j) v1[j] = as[j][t];
            float* X2Tp = ws + OFF_X2T + b * 32768 + t * 128 + l0b;
            float4 r0 = {v1[0], v1[1], v1[2], v1[3]};
            float4 r1 = {v1[4], v1[5], v1[6], v1[7]};
            *(float4*)X2Tp = r0; *(float4*)(X2Tp + 4) = r1;
        }
        // stage 1: gZ2 = X2 @ W2T + b2 - V
        {
            const float* W2t = ws + OFF_W2T + b * 65536;
            float4 a0 = dot256(as, tok, W2t + c, 256);
            float4 a1 = dot256(as, tok, W2t + c2, 256);
            float4 bb0 = *(const float4*)(p.b2 + b * 256 + c);
            float4 bb1 = *(const float4*)(p.b2 + b * 256 + c2);
            float4 v0 = *(const float4*)(ws + OFF_V + (bl0 + tok) * 256 + c);
            float4 v1 = *(const float4*)(ws + OFF_V + (bl0 + tok) * 256 + c2);
            float4 g0 = {a0.x + bb0.x - v0.x, a0.y + bb0.y - v0.y,
                         a0.z + bb0.z - v0.z, a0.w + bb0.w - v0.w};
            float4 g1 = {a1.x + bb1.x - v1.x, a1.y + bb1.y - v1.y,
                         a1.z + bb1.z - v1.z, a1.w + bb1.w - v1.w};
            *(float4*)&gs[tok][c]  = g0;
            *(float4*)&gs[tok][c2] = g1;
            *(float4*)(ws + OFF_GZ2 + (bl0 + tok) * 256 + c)  = g0;
            *(float4*)(ws + OFF_GZ2 + (bl0 + tok) * 256 + c2) = g1;
        }
        __syncthreads();
        // stage 2: gX2 = gZ2 @ W2(native); gZ1 = gX2 * silu'(Z1)
        {
            const float* W2n = p.W2 + b * 65536;
            float4 a0 = dot256(gs, tok, W2n + c, 256);
            float4 a1 = dot256(gs, tok, W2n + c2, 256);
            float4 z0 = *(float4*)&zs[tok][c];
            float4 z1 = *(float4*)&zs[tok][c2];
            float4 g0 = {dsilu_mul(a0.x, z0.x), dsilu_mul(a0.y, z0.y),
                         dsilu_mul(a0.z, z0.z), dsilu_mul(a0.w, z0.w)};
            float4 g1 = {dsilu_mul(a1.x, z1.x), dsilu_mul(a1.y, z1.y),
                         dsilu_mul(a1.z, z1.z), dsilu_mul(a1.w, z1.w)};
            *(float4*)(ws + OFF_GZ1 + (bl0 + tok) * 256 + c)  = g0;
            *(float4*)(ws + OFF_GZ1 + (bl0 + tok) * 256 + c2) = g1;
        }
    } else if (u < 160) {
        // U1 (mat=0) / V1 (mat=1)
        int w = u - 32; int mat = w >> 6; int r = w & 63;
        int tt = r >> 1, ct = r & 1;
        int bl0 = tt * 8, c0 = ct * 128, b = bl0 >> 7;
        float (*xs)[260] = (float (*)[260])smem;
        stage8(ws + OFF_Q + bl0 * 256, xs, t);
        __syncthreads();
        int tok = t >> 5, q = t & 31;
        int c = c0 + 4 * q;
        const float* W = ws + (mat ? OFF_MW1T : OFF_W1T) + b * 65536 + c;
        const float* bias = (mat ? p.mb1 : p.b1) + b * 256 + c;
        float4 a = dot256(xs, tok, W, 256);
        float4 bb = *(const float4*)bias;
        a.x += bb.x; a.y += bb.y; a.z += bb.z; a.w += bb.w;
        *(float4*)(ws + (mat ? OFF_V1 : OFF_U1) + (bl0 + tok) * 256 + c) = a;
    } else {
        // scan + A-row (R6-verified per-row parallel form)
        int w = u - 160; int b = w >> 7; int l = w & 127;
        float* sm = smem;
        float* sd = smem + 128;
        float* se = smem + 256;
        if (t < 128) {
            sm[t] = ws[OFF_LOGM + b * Ln + t];
            sd[t] = ws[OFF_LOGWD + b * Ln + t];
        }
        __syncthreads();
        for (int off = 1; off < 128; off <<= 1) {
            float am = 0.0f, ad = 0.0f;
            if (t < 128 && t >= off) { am = sm[t - off]; ad = sd[t - off]; }
            __syncthreads();
            if (t < 128) { sm[t] += am; sd[t] += ad; }
            __syncthreads();
        }
        if (l == 0) {
            if (t < 128) {
                float pm = sm[t], pd = sd[t];
                ws[OFF_PM + b * Ln + t] = pm;
                ws[OFF_PD + b * Ln + t] = pd;
                ws[OFF_MOMCUM + b * Ln + t] = expf(pm);
                ws[OFF_WDCUM + b * Ln + t]  = expf(pd);
                se[t] = expf(pm - pd);
            }
            __syncthreads();
            for (int off = 1; off < 128; off <<= 1) {
                float a = 0.0f;
                if (t < 128 && t >= off) a = se[t - off];
                __syncthreads();
                if (t < 128) se[t] += a;
                __syncthreads();
            }
            if (t < 128) ws[OFF_C + b * Ln + t] = expf(sd[t]) * se[t];
        }
        if (t < 128) {
            int m1 = t;
            float a = 0.0f;
            if (m1 <= l) {
                float pdl = sd[l], pmm1 = sm[m1];
                float s = 0.0f;
                for (int m = m1; m <= l; ++m)
                    s += expf((pdl - sd[m]) + (sm[m] - pmm1));
                a = s;
            }
            ws[OFF_A + (b * Ln + l) * Ln + m1] = a;
        }
    }
}

// ---------------------------------------------------------------------------
// Phase 2: fused score1->combine1 -> XQ (64u) + lastw (1024u) + lastb (2u)
// ---------------------------------------------------------------------------
__global__ __launch_bounds__(256) void phase2_kernel(KParams p) {
    __shared__ float smem[6400];
    int u = blockIdx.x, t = threadIdx.x;
    float* ws = p.ws;
    if (u < 64) {
        int b = u >> 5; int rem = u & 31;
        int l0 = (rem >> 1) * 8; int c0 = (rem & 1) * 128;
        score_combine_unit(p, smem, t, b, l0, c0, OFF_Q, OFF_KT, OFF_GZ1,
                           OFF_U1, OFF_V1, 1, ws + OFF_XQ);
    } else if (u < 1088) {
        int w = u - 64; int z = w >> 8; int rem = w & 255;
        int b = z >> 1; int fam = z & 1;
        lastw_unit(p, smem, t, b, fam, (rem >> 4) * 16, (rem & 15) * 16);
    } else {
        int b = u - 1088;
        float* wa = smem;
        float* wm = smem + 128;
        if (t < 128) {
            wa[t] = ws[OFF_A + (b * Ln + Ln - 1) * Ln + t] * ws[OFF_LR + b * Ln + t];
            wm[t] = expf(ws[OFF_PM + b * Ln + Ln - 1] - ws[OFF_PM + b * Ln + t]) *
                    ws[OFF_LR + b * Ln + t];
        }
        __syncthreads();
        const float* gz1 = ws + OFF_GZ1 + b * Ln * 256;
        const float* gz2 = ws + OFF_GZ2 + b * Ln * 256;
        float sA1 = 0, sM1 = 0, sA2 = 0, sM2 = 0;
        for (int m0 = 0; m0 < 128; m0 += 16) {
            float g1b[16], g2b[16];
#pragma unroll
            for (int kk = 0; kk < 16; ++kk) {
                g1b[kk] = gz1[(m0 + kk) * 256 + t];
                g2b[kk] = gz2[(m0 + kk) * 256 + t];
            }
#pragma unroll
            for (int kk = 0; kk < 16; ++kk) {
                float wam = wa[m0 + kk], wmm = wm[m0 + kk];
                sA1 += wam * g1b[kk]; sM1 += wmm * g1b[kk];
                sA2 += wam * g2b[kk]; sM2 += wmm * g2b[kk];
            }
        }
        float c_last  = ws[OFF_C + b * Ln + Ln - 1];
        float wd_last = ws[OFF_WDCUM + b * Ln + Ln - 1];
        float mc_last = ws[OFF_MOMCUM + b * Ln + Ln - 1];
        p.out[OUT_B1P + b * 256 + t]  = sA1 - c_last * p.mb1[b * 256 + t] + wd_last * p.b1[b * 256 + t];
        p.out[OUT_MGB1 + b * 256 + t] = sM1 - mc_last * p.mb1[b * 256 + t];
        p.out[OUT_B2P + b * 256 + t]  = sA2 - c_last * p.mb2[b * 256 + t] + wd_last * p.b2[b * 256 + t];
        p.out[OUT_MGB2 + b * 256 + t] = sM2 - mc_last * p.mb2[b * 256 + t];
    }
}

// ---------------------------------------------------------------------------
// Phase 3: U2 (64u) + V2 (64u) = 128
// ---------------------------------------------------------------------------
__global__ __launch_bounds__(256) void phase3_kernel(KParams p) {
    __shared__ float smem[4160];
    int u = blockIdx.x, t = threadIdx.x;
    float* ws = p.ws;
    int mat = u >> 6; int r = u & 63;
    int tt = r >> 1, ct = r & 1;
    int bl0 = tt * 8, c0 = ct * 128, b = bl0 >> 7;
    float (*xs)[260] = (float (*)[260])smem;
    stage8(ws + OFF_XQ + bl0 * 256, xs, t);
    __syncthreads();
    int tok = t >> 5, q = t & 31;
    int c = c0 + 4 * q;
    const float* W = ws + (mat ? OFF_MW2T : OFF_W2T) + b * 65536 + c;
    const float* bias = (mat ? p.mb2 : p.b2) + b * 256 + c;
    float4 a = dot256(xs, tok, W, 256);
    float4 bb = *(const float4*)bias;
    a.x += bb.x; a.y += bb.y; a.z += bb.z; a.w += bb.w;
    *(float4*)(ws + (mat ? OFF_V2 : OFF_U2) + (bl0 + tok) * 256 + c) = a;
}

// ---------------------------------------------------------------------------
// Phase 4: fused score2->combine2 -> out ZQ2 (64u)
// ---------------------------------------------------------------------------
__global__ __launch_bounds__(256) void phase4_kernel(KParams p) {
    __shared__ float smem[3136];
    int u = blockIdx.x, t = threadIdx.x;
    int b = u >> 5; int rem = u & 31;
    int l0 = (rem >> 1) * 8; int c0 = (rem & 1) * 128;
    score_combine_unit(p, smem, t, b, l0, c0, OFF_XQ, OFF_X2T, OFF_GZ2,
                       OFF_U2, OFF_V2, 0, p.out + OUT_ZQ2);
}

// ---------------------------------------------------------------------------
extern "C" void kernel_launch(void* const* d_in, const int* in_sizes, int n_in,
                              void* d_out, int out_size, void* d_ws, size_t ws_size,
                              hipStream_t stream) {
    KParams p;
    p.x   = (const float*)d_in[0];
    p.Wq  = (const float*)d_in[1];  p.bq  = (const float*)d_in[2];
    p.Wk  = (const float*)d_in[3];  p.bk  = (const float*)d_in[4];
    p.Wv  = (const float*)d_in[5];  p.bv  = (const float*)d_in[6];
    p.Wlr = (const float*)d_in[7];  p.blr = (const float*)d_in[8];
    p.Wm  = (const float*)d_in[9];  p.bm  = (const float*)d_in[10];
    p.Wd  = (const float*)d_in[11]; p.bd  = (const float*)d_in[12];
    p.W1  = (const float*)d_in[13]; p.b1  = (const float*)d_in[14];
    p.W2  = (const float*)d_in[15]; p.b2  = (const float*)d_in[16];
    p.mW1 = (const float*)d_in[17]; p.mb1 = (const float*)d_in[18];
    p.mW2 = (const float*)d_in[19]; p.mb2 = (const float*)d_in[20];
    p.out = (float*)d_out;
    p.ws  = (float*)d_ws;

    phase0_kernel<<<768, 256, 0, stream>>>(p);
    phase1_kernel<<<416, 256, 0, stream>>>(p);
    phase2_kernel<<<1090, 256, 0, stream>>>(p);
    phase3_kernel<<<128, 256, 0, stream>>>(p);
    phase4_kernel<<<64, 256, 0, stream>>>(p);
}

// Round 11
// 206.651 us; speedup vs baseline: 2.7282x; 1.0464x over previous
//
#include <hip/hip_runtime.h>
#include <math.h>

// Problem constants
constexpr int Bn = 2, Ln = 128, Dn = 256, Hn = 256;

// log(expm1(0.01))
#define LR_SHIFT (-4.6001660040607144f)

// Workspace offsets (floats)
constexpr int OFF_Q      = 0;        // [B,L,D]
constexpr int OFF_K      = 65536;    // [B,L,D]
constexpr int OFF_V      = 131072;   // [B,L,D]
constexpr int OFF_X2     = 196608;   // [B,L,H]
constexpr int OFF_GZ1    = 262144;   // [B,L,H]  (Z1 parked here between P1 and P2)
constexpr int OFF_GZ2    = 327680;   // [B,L,D]
constexpr int OFF_XQ     = 393216;   // [B,L,H]
constexpr int OFF_KT     = 458752;   // [B,256,128]
constexpr int OFF_A      = 524288;   // [B,L,L]
constexpr int OFF_W1T    = 557056;   // [B,D,H]
constexpr int OFF_W2T    = 688128;   // [B,H,D]
constexpr int OFF_MW1T   = 819200;   // [B,D,H]
constexpr int OFF_MW2T   = 950272;   // [B,H,D]
constexpr int OFF_LR     = 1081344;  // [B,L]
constexpr int OFF_PM     = 1081600;  // [B,L]
constexpr int OFF_PD     = 1081856;  // [B,L]
constexpr int OFF_MOMCUM = 1082112;  // [B,L]
constexpr int OFF_WDCUM  = 1082368;  // [B,L]
constexpr int OFF_C      = 1082624;  // [B,L]
constexpr int OFF_LOGM   = 1082880;  // [B,L]
constexpr int OFF_LOGWD  = 1083136;  // [B,L]
constexpr int OFF_X2T    = 1083392;  // [B,256,128]
constexpr int OFF_U1     = 1148928;  // [B*L,256]  Q@W1T + b1
constexpr int OFF_V1     = 1214464;  // [B*L,256]  Q@mW1T + mb1
constexpr int OFF_U2     = 1280000;  // [B*L,256]  XQ@W2T + b2
constexpr int OFF_V2     = 1345536;  // [B*L,256]  XQ@mW2T + mb2
constexpr int OFF_P1     = 1411072;  // [B,128,128]  score1, later score2
// total 1443840 floats ~= 5.8 MB

// Output offsets (floats)
constexpr int OUT_ZQ2  = 0;
constexpr int OUT_W1P  = 65536;
constexpr int OUT_B1P  = 196608;
constexpr int OUT_W2P  = 197120;
constexpr int OUT_B2P  = 328192;
constexpr int OUT_MGW1 = 328704;
constexpr int OUT_MGB1 = 459776;
constexpr int OUT_MGW2 = 460288;
constexpr int OUT_MGB2 = 591360;

struct KParams {
    const float *x;
    const float *Wq, *bq, *Wk, *bk, *Wv, *bv;
    const float *Wlr, *blr, *Wm, *bm, *Wd, *bd;
    const float *W1, *b1, *W2, *b2, *mW1, *mb1, *mW2, *mb2;
    float *out, *ws;
};

__device__ __forceinline__ float softplus_f(float z) {
    return fmaxf(z, 0.0f) + log1pf(expf(-fabsf(z)));
}
__device__ __forceinline__ float4 fma4(float s, const float4 w, float4 a) {
    a.x += s * w.x; a.y += s * w.y; a.z += s * w.z; a.w += s * w.w; return a;
}
__device__ __forceinline__ float silu_f(float z) {
    return z / (1.0f + expf(-z));
}
__device__ __forceinline__ float dsilu_mul(float a, float z) {
    float sg = 1.0f / (1.0f + expf(-z));
    return a * (sg * (1.0f + z * (1.0f - sg)));
}

// stage 8 rows of 256 floats into LDS [8][260]
__device__ __forceinline__ void stage8(const float* __restrict__ src,
                                       float (*xs)[260], int t) {
#pragma unroll
    for (int i = 0; i < 2; ++i) {
        int e = t + i * 256; int tok = e >> 6, kq = e & 63;
        *(float4*)&xs[tok][kq * 4] = *(const float4*)(src + tok * 256 + kq * 4);
    }
}

// acc = sum_k xs[tok][k] * W[k*ldw + 0..3], k=0..255, 16-deep batches
__device__ __forceinline__ float4 dot256(const float (*xs)[260], int tok,
                                         const float* __restrict__ Wc, int ldw) {
    float4 a = {0, 0, 0, 0};
    for (int k0 = 0; k0 < 256; k0 += 16) {
        float4 wb[16];
#pragma unroll
        for (int kk = 0; kk < 16; ++kk)
            wb[kk] = *(const float4*)(Wc + (k0 + kk) * ldw);
#pragma unroll
        for (int kk = 0; kk < 16; ++kk)
            a = fma4(xs[tok][k0 + kk], wb[kk], a);
    }
    return a;
}

// last-token weight-output tile (16x16), fam: 0 -> W1p/mgW1, 1 -> W2p/mgW2
__device__ __forceinline__ void lastw_unit(const KParams& p, float* smem, int t,
                                           int b, int fam, int i0, int j0) {
    const float* ws = p.ws;
    float* wa = smem;
    float* wm = smem + 128;
    float (*LA)[16] = (float (*)[16])(smem + 256);
    float (*LM)[16] = (float (*)[16])(smem + 256 + 2048);
    float (*R)[16]  = (float (*)[16])(smem + 256 + 4096);
    const float* lr = ws + OFF_LR + b * Ln;
    const float* Pm = ws + OFF_PM + b * Ln;
    const float* Arow = ws + OFF_A + (b * Ln + Ln - 1) * Ln;
    if (t < 128) {
        wa[t] = Arow[t] * lr[t];
        wm[t] = expf(Pm[Ln - 1] - Pm[t]) * lr[t];
    }
    const float* left  = ws + (fam == 0 ? OFF_GZ1 : OFF_GZ2) + b * Ln * 256;
    const float* right = ws + (fam == 0 ? OFF_K   : OFF_X2 ) + b * Ln * 256;
    __syncthreads();
#pragma unroll
    for (int i = 0; i < 2; ++i) {
        int e = t + i * 256;
        int m = e >> 2, iq = (e & 3) * 4;
        float4 lv = *(const float4*)(left + m * 256 + i0 + iq);
        float4 rv = *(const float4*)(right + m * 256 + j0 + iq);
        float wam = wa[m], wmm = wm[m];
        LA[m][iq + 0] = wam * lv.x; LA[m][iq + 1] = wam * lv.y;
        LA[m][iq + 2] = wam * lv.z; LA[m][iq + 3] = wam * lv.w;
        LM[m][iq + 0] = wmm * lv.x; LM[m][iq + 1] = wmm * lv.y;
        LM[m][iq + 2] = wmm * lv.z; LM[m][iq + 3] = wmm * lv.w;
        R[m][iq + 0] = rv.x; R[m][iq + 1] = rv.y;
        R[m][iq + 2] = rv.z; R[m][iq + 3] = rv.w;
    }
    __syncthreads();
    int tx = t & 15, ty = t >> 4;
    float accA = 0.0f, accM = 0.0f;
#pragma unroll 4
    for (int m = 0; m < 128; ++m) {
        accA += LA[m][ty] * R[m][tx];
        accM += LM[m][ty] * R[m][tx];
    }
    float c_last  = ws[OFF_C + b * Ln + Ln - 1];
    float wd_last = ws[OFF_WDCUM + b * Ln + Ln - 1];
    float mc_last = ws[OFF_MOMCUM + b * Ln + Ln - 1];
    int i = i0 + ty, j = j0 + tx;
    const float* base1 = (fam == 0 ? p.W1 : p.W2) + b * 65536;
    const float* basem = (fam == 0 ? p.mW1 : p.mW2) + b * 65536;
    float b1v = base1[i * 256 + j], bmv = basem[i * 256 + j];
    int op = (fam == 0 ? OUT_W1P : OUT_W2P) + (b * 256 + i) * 256 + j;
    int om = (fam == 0 ? OUT_MGW1 : OUT_MGW2) + (b * 256 + i) * 256 + j;
    p.out[op] = accA - c_last * bmv + wd_last * b1v;
    p.out[om] = accM - mc_last * bmv;
}

// score tile: 8 l-rows x 128 m (src rows from global, P to global)
__device__ __forceinline__ void score_unit(const KParams& p, float* smem, int t,
                                           int b, int l0, int srcoff, int btoff,
                                           int poff) {
    const float* ws = p.ws;
    float (*qs)[260] = (float (*)[260])smem;
    stage8(ws + srcoff + (b * 128 + l0) * 256, qs, t);
    __syncthreads();
    int tok = t >> 5, mq = t & 31, m0 = 4 * mq;
    int l = l0 + tok;
    float4 s = dot256(qs, tok, ws + btoff + b * 32768 + m0, 128);
    float4 A4 = *(const float4*)(ws + OFF_A + (b * 128 + l) * 128 + m0);
    float4 L4 = *(const float4*)(ws + OFF_LR + b * 128 + m0);
    float4 pv;
    pv.x = (m0 + 0 <= l) ? A4.x * L4.x * (1.0f + s.x) : 0.0f;
    pv.y = (m0 + 1 <= l) ? A4.y * L4.y * (1.0f + s.y) : 0.0f;
    pv.z = (m0 + 2 <= l) ? A4.z * L4.z * (1.0f + s.z) : 0.0f;
    pv.w = (m0 + 3 <= l) ? A4.w * L4.w * (1.0f + s.w) : 0.0f;
    *(float4*)(p.ws + poff + b * 16384 + l * 128 + m0) = pv;
}

// P@G contraction for one token/col-quad: 16-deep main + 8-deep tail
__device__ __forceinline__ float4 pg_dot(const float* __restrict__ G,
                                         const float* __restrict__ prow,
                                         int mmax) {
    float4 acc = {0, 0, 0, 0};
    int m0 = 0;
    for (; m0 + 16 <= mmax; m0 += 16) {
        float4 gb[16];
#pragma unroll
        for (int kk = 0; kk < 16; ++kk)
            gb[kk] = *(const float4*)(G + (m0 + kk) * 256);
#pragma unroll
        for (int kk = 0; kk < 16; ++kk)
            acc = fma4(prow[m0 + kk], gb[kk], acc);
    }
    for (; m0 < mmax; m0 += 8) {
        float4 gb[8];
#pragma unroll
        for (int kk = 0; kk < 8; ++kk)
            gb[kk] = *(const float4*)(G + (m0 + kk) * 256);
#pragma unroll
        for (int kk = 0; kk < 8; ++kk)
            acc = fma4(prow[m0 + kk], gb[kk], acc);
    }
    return acc;
}

// combine tile: out = P@G - cl*V + wd*U (optionally silu) for 8 tok x 128 c
__device__ __forceinline__ void combine_unit(const KParams& p, float* smem, int t,
                                             int b, int l0, int c0, int poff,
                                             int goff, int uoff, int voff,
                                             int dooutsilu, float* dst) {
    const float* ws = p.ws;
    int bl0 = b * 128 + l0;
    float (*ps)[132] = (float (*)[132])smem;
    {
        int tok = t >> 5, mq = t & 31;
        *(float4*)&ps[tok][mq * 4] =
            *(const float4*)(ws + poff + b * 16384 + (l0 + tok) * 128 + mq * 4);
    }
    __syncthreads();
    int tok = t >> 5, q = t & 31;
    int l = l0 + tok;
    int c = c0 + 4 * q;
    float cl  = ws[OFF_C + b * 128 + l];
    float wdc = ws[OFF_WDCUM + b * 128 + l];
    float4 acc = pg_dot(ws + goff + b * 32768 + c, ps[tok], l0 + 8);
    float4 u4 = *(const float4*)(ws + uoff + (bl0 + tok) * 256 + c);
    float4 v4 = *(const float4*)(ws + voff + (bl0 + tok) * 256 + c);
    float4 o;
    o.x = acc.x - cl * v4.x + wdc * u4.x;
    o.y = acc.y - cl * v4.y + wdc * u4.y;
    o.z = acc.z - cl * v4.z + wdc * u4.z;
    o.w = acc.w - cl * v4.w + wdc * u4.w;
    if (dooutsilu) {
        o.x = silu_f(o.x); o.y = silu_f(o.y); o.z = silu_f(o.z); o.w = silu_f(o.w);
    }
    *(float4*)(dst + (bl0 + tok) * 256 + c) = o;
}

// ---------------------------------------------------------------------------
// Phase 0 (R6-verified): transposes (512u) + QKV (192u, +KT) + scalproj (64u)
// ---------------------------------------------------------------------------
__global__ __launch_bounds__(256) void phase0_kernel(KParams p) {
    __shared__ float smem[4160];
    int u = blockIdx.x, t = threadIdx.x;
    float* ws = p.ws;
    if (u < 512) {
        int z = u >> 6; int mat = z >> 1; int b = z & 1;
        const float* src; float* dst;
        if (mat == 0)      { src = p.W1  + b * 65536; dst = ws + OFF_W1T  + b * 65536; }
        else if (mat == 1) { src = p.W2  + b * 65536; dst = ws + OFF_W2T  + b * 65536; }
        else if (mat == 2) { src = p.mW1 + b * 65536; dst = ws + OFF_MW1T + b * 65536; }
        else               { src = p.mW2 + b * 65536; dst = ws + OFF_MW2T + b * 65536; }
        float (*tile)[33] = (float (*)[33])smem;
        int tx = t & 31, ty = t >> 5;
        int tid = u & 63;
        int r0 = (tid >> 3) * 32, c0 = (tid & 7) * 32;
        for (int i = 0; i < 32; i += 8)
            tile[ty + i][tx] = src[(r0 + ty + i) * 256 + (c0 + tx)];
        __syncthreads();
        for (int i = 0; i < 32; i += 8)
            dst[(c0 + ty + i) * 256 + (r0 + tx)] = tile[tx][ty + i];
    } else if (u < 704) {
        int v = u - 512; int mat = v >> 6; int r = v & 63;
        int ct = r >> 5, tt = r & 31;
        int bl0 = tt * 8, c0 = ct * 128;
        const float* W    = (mat == 0) ? p.Wq : (mat == 1) ? p.Wk : p.Wv;
        const float* bias = (mat == 0) ? p.bq : (mat == 1) ? p.bk : p.bv;
        int outoff = (mat == 0) ? OFF_Q : (mat == 1) ? OFF_K : OFF_V;
        float (*xs)[260] = (float (*)[260])smem;
        stage8(p.x + bl0 * 256, xs, t);
        __syncthreads();
        int tok = t >> 5, q = t & 31;
        int c = c0 + 4 * q;
        float4 a = dot256(xs, tok, W + c, 256);
        float4 bb = *(const float4*)(bias + c);
        a.x += bb.x; a.y += bb.y; a.z += bb.z; a.w += bb.w;
        *(float4*)(ws + outoff + (bl0 + tok) * 256 + c) = a;
        if (mat == 1) {
            int b = bl0 >> 7, l = (bl0 & 127) + tok;
            float* KT = ws + OFF_KT + b * 32768 + l;
            KT[(c + 0) * 128] = a.x; KT[(c + 1) * 128] = a.y;
            KT[(c + 2) * 128] = a.z; KT[(c + 3) * 128] = a.w;
        }
    } else {
        int blk = u - 704;
        int ln = t & 63, wv = t >> 6;
        int bl = blk * 4 + wv;
        float4 xv = *(const float4*)(p.x + bl * 256 + ln * 4);
        float4 wl = *(const float4*)(p.Wlr + ln * 4);
        float4 wm = *(const float4*)(p.Wm + ln * 4);
        float4 wd = *(const float4*)(p.Wd + ln * 4);
        float s1 = xv.x * wl.x + xv.y * wl.y + xv.z * wl.z + xv.w * wl.w;
        float s2 = xv.x * wm.x + xv.y * wm.y + xv.z * wm.z + xv.w * wm.w;
        float s3 = xv.x * wd.x + xv.y * wd.y + xv.z * wd.z + xv.w * wd.w;
#pragma unroll
        for (int off = 32; off > 0; off >>= 1) {
            s1 += __shfl_xor(s1, off);
            s2 += __shfl_xor(s2, off);
            s3 += __shfl_xor(s3, off);
        }
        if (ln == 0) {
            ws[OFF_LR + bl]    = softplus_f(s1 + p.blr[0] + LR_SHIFT);
            ws[OFF_LOGM + bl]  = -softplus_f(-(s2 + p.bm[0]));
            ws[OFF_LOGWD + bl] = -softplus_f(s3 + p.bd[0]);
        }
    }
}

// ---------------------------------------------------------------------------
// Phase 1 (R6-verified): stage0 Z1/X2/X2T (64u) + scan/A (256u) + U1/V1 (128u)
// ---------------------------------------------------------------------------
__global__ __launch_bounds__(256) void phase1_kernel(KParams p) {
    __shared__ float smem[4160];
    int u = blockIdx.x, t = threadIdx.x;
    float* ws = p.ws;
    if (u < 64) {
        int tt = u >> 1, ct = u & 1;
        int bl0 = tt * 8, c0 = ct * 128, b = bl0 >> 7;
        float (*xs)[260] = (float (*)[260])smem;
        stage8(ws + OFF_K + bl0 * 256, xs, t);
        __syncthreads();
        int tok = t >> 5, q = t & 31;
        int c = c0 + 4 * q;
        float4 a = dot256(xs, tok, ws + OFF_W1T + b * 65536 + c, 256);
        float4 bb = *(const float4*)(p.b1 + b * 256 + c);
        float4 z = {a.x + bb.x, a.y + bb.y, a.z + bb.z, a.w + bb.w};
        *(float4*)(ws + OFF_GZ1 + (bl0 + tok) * 256 + c) = z;  // park Z1
        float4 s = {silu_f(z.x), silu_f(z.y), silu_f(z.z), silu_f(z.w)};
        *(float4*)(ws + OFF_X2 + (bl0 + tok) * 256 + c) = s;
        int l = (bl0 & 127) + tok;
        float* X2T = ws + OFF_X2T + b * 32768 + l;
        X2T[(c + 0) * 128] = s.x; X2T[(c + 1) * 128] = s.y;
        X2T[(c + 2) * 128] = s.z; X2T[(c + 3) * 128] = s.w;
    } else if (u < 320) {
        int w = u - 64; int b = w >> 7; int l = w & 127;
        float* sm = smem;
        float* sd = smem + 128;
        float* se = smem + 256;
        if (t < 128) {
            sm[t] = ws[OFF_LOGM + b * Ln + t];
            sd[t] = ws[OFF_LOGWD + b * Ln + t];
        }
        __syncthreads();
        for (int off = 1; off < 128; off <<= 1) {
            float am = 0.0f, ad = 0.0f;
            if (t < 128 && t >= off) { am = sm[t - off]; ad = sd[t - off]; }
            __syncthreads();
            if (t < 128) { sm[t] += am; sd[t] += ad; }
            __syncthreads();
        }
        if (l == 0) {
            if (t < 128) {
                float pm = sm[t], pd = sd[t];
                ws[OFF_PM + b * Ln + t] = pm;
                ws[OFF_PD + b * Ln + t] = pd;
                ws[OFF_MOMCUM + b * Ln + t] = expf(pm);
                ws[OFF_WDCUM + b * Ln + t]  = expf(pd);
                se[t] = expf(pm - pd);
            }
            __syncthreads();
            for (int off = 1; off < 128; off <<= 1) {
                float a = 0.0f;
                if (t < 128 && t >= off) a = se[t - off];
                __syncthreads();
                if (t < 128) se[t] += a;
                __syncthreads();
            }
            if (t < 128) ws[OFF_C + b * Ln + t] = expf(sd[t]) * se[t];
        }
        if (t < 128) {
            int m1 = t;
            float a = 0.0f;
            if (m1 <= l) {
                float pdl = sd[l], pmm1 = sm[m1];
                float s = 0.0f;
                for (int m = m1; m <= l; ++m)
                    s += expf((pdl - sd[m]) + (sm[m] - pmm1));
                a = s;
            }
            ws[OFF_A + (b * Ln + l) * Ln + m1] = a;
        }
    } else {
        // U1 (mat=0) / V1 (mat=1)
        int w = u - 320; int mat = w >> 6; int r = w & 63;
        int tt = r >> 1, ct = r & 1;
        int bl0 = tt * 8, c0 = ct * 128, b = bl0 >> 7;
        float (*xs)[260] = (float (*)[260])smem;
        stage8(ws + OFF_Q + bl0 * 256, xs, t);
        __syncthreads();
        int tok = t >> 5, q = t & 31;
        int c = c0 + 4 * q;
        const float* W = ws + (mat ? OFF_MW1T : OFF_W1T) + b * 65536 + c;
        const float* bias = (mat ? p.mb1 : p.b1) + b * 256 + c;
        float4 a = dot256(xs, tok, W, 256);
        float4 bb = *(const float4*)bias;
        a.x += bb.x; a.y += bb.y; a.z += bb.z; a.w += bb.w;
        *(float4*)(ws + (mat ? OFF_V1 : OFF_U1) + (bl0 + tok) * 256 + c) = a;
    }
}

// ---------------------------------------------------------------------------
// Phase 2: fused gZ2->gZ1 (32u, chain 32, R8-verified) + score1 (32u) = 64
// ---------------------------------------------------------------------------
__global__ __launch_bounds__(256) void phase2_kernel(KParams p) {
    __shared__ float smem[4160];
    int u = blockIdx.x, t = threadIdx.x;
    float* ws = p.ws;
    if (u < 32) {
        int bl0 = u * 8, b = bl0 >> 7;
        float (*xs)[260] = (float (*)[260])smem;           // X2 rows
        float (*gs)[260] = (float (*)[260])(smem + 2080);  // gZ2 rows
        stage8(ws + OFF_X2 + bl0 * 256, xs, t);
        __syncthreads();
        int tok = t >> 5, q = t & 31;
        int c = 4 * q, c2 = c + 128;
        // gZ2 = X2 @ W2T + b2 - V  (both col-halves)
        {
            const float* W2t = ws + OFF_W2T + b * 65536;
            float4 a0 = dot256(xs, tok, W2t + c, 256);
            float4 a1 = dot256(xs, tok, W2t + c2, 256);
            float4 bb0 = *(const float4*)(p.b2 + b * 256 + c);
            float4 bb1 = *(const float4*)(p.b2 + b * 256 + c2);
            float4 v0 = *(const float4*)(ws + OFF_V + (bl0 + tok) * 256 + c);
            float4 v1 = *(const float4*)(ws + OFF_V + (bl0 + tok) * 256 + c2);
            float4 g0 = {a0.x + bb0.x - v0.x, a0.y + bb0.y - v0.y,
                         a0.z + bb0.z - v0.z, a0.w + bb0.w - v0.w};
            float4 g1 = {a1.x + bb1.x - v1.x, a1.y + bb1.y - v1.y,
                         a1.z + bb1.z - v1.z, a1.w + bb1.w - v1.w};
            *(float4*)&gs[tok][c]  = g0;
            *(float4*)&gs[tok][c2] = g1;
            *(float4*)(ws + OFF_GZ2 + (bl0 + tok) * 256 + c)  = g0;
            *(float4*)(ws + OFF_GZ2 + (bl0 + tok) * 256 + c2) = g1;
        }
        __syncthreads();
        // gX2 = gZ2 @ W2(native); gZ1 = gX2 * silu'(Z1)
        {
            const float* W2n = p.W2 + b * 65536;
            float4 a0 = dot256(gs, tok, W2n + c, 256);
            float4 a1 = dot256(gs, tok, W2n + c2, 256);
            float4 z0 = *(const float4*)(ws + OFF_GZ1 + (bl0 + tok) * 256 + c);
            float4 z1 = *(const float4*)(ws + OFF_GZ1 + (bl0 + tok) * 256 + c2);
            float4 g0 = {dsilu_mul(a0.x, z0.x), dsilu_mul(a0.y, z0.y),
                         dsilu_mul(a0.z, z0.z), dsilu_mul(a0.w, z0.w)};
            float4 g1 = {dsilu_mul(a1.x, z1.x), dsilu_mul(a1.y, z1.y),
                         dsilu_mul(a1.z, z1.z), dsilu_mul(a1.w, z1.w)};
            *(float4*)(ws + OFF_GZ1 + (bl0 + tok) * 256 + c)  = g0;
            *(float4*)(ws + OFF_GZ1 + (bl0 + tok) * 256 + c2) = g1;
        }
    } else {
        int w = u - 32; int b = w >> 4; int l0 = (w & 15) * 8;
        score_unit(p, smem, t, b, l0, OFF_Q, OFF_KT, OFF_P1);
    }
}

// ---------------------------------------------------------------------------
// Phase 3: combine1 -> XQ (64u, chain 9) + lastw both fams (1024u) + lastb (2u)
// ---------------------------------------------------------------------------
__global__ __launch_bounds__(256) void phase3_kernel(KParams p) {
    __shared__ float smem[6400];
    int u = blockIdx.x, t = threadIdx.x;
    float* ws = p.ws;
    if (u < 64) {
        int tt = u >> 1, ct = u & 1;
        int b = tt >> 4, l0 = (tt & 15) * 8;
        combine_unit(p, smem, t, b, l0, ct * 128, OFF_P1, OFF_GZ1,
                     OFF_U1, OFF_V1, 1, ws + OFF_XQ);
    } else if (u < 1088) {
        int w = u - 64; int z = w >> 8; int rem = w & 255;
        int b = z >> 1; int fam = z & 1;
        lastw_unit(p, smem, t, b, fam, (rem >> 4) * 16, (rem & 15) * 16);
    } else {
        int b = u - 1088;
        float* wa = smem;
        float* wm = smem + 128;
        if (t < 128) {
            wa[t] = ws[OFF_A + (b * Ln + Ln - 1) * Ln + t] * ws[OFF_LR + b * Ln + t];
            wm[t] = expf(ws[OFF_PM + b * Ln + Ln - 1] - ws[OFF_PM + b * Ln + t]) *
                    ws[OFF_LR + b * Ln + t];
        }
        __syncthreads();
        const float* gz1 = ws + OFF_GZ1 + b * Ln * 256;
        const float* gz2 = ws + OFF_GZ2 + b * Ln * 256;
        float sA1 = 0, sM1 = 0, sA2 = 0, sM2 = 0;
        for (int m0 = 0; m0 < 128; m0 += 16) {
            float g1b[16], g2b[16];
#pragma unroll
            for (int kk = 0; kk < 16; ++kk) {
                g1b[kk] = gz1[(m0 + kk) * 256 + t];
                g2b[kk] = gz2[(m0 + kk) * 256 + t];
            }
#pragma unroll
            for (int kk = 0; kk < 16; ++kk) {
                float wam = wa[m0 + kk], wmm = wm[m0 + kk];
                sA1 += wam * g1b[kk]; sM1 += wmm * g1b[kk];
                sA2 += wam * g2b[kk]; sM2 += wmm * g2b[kk];
            }
        }
        float c_last  = ws[OFF_C + b * Ln + Ln - 1];
        float wd_last = ws[OFF_WDCUM + b * Ln + Ln - 1];
        float mc_last = ws[OFF_MOMCUM + b * Ln + Ln - 1];
        p.out[OUT_B1P + b * 256 + t]  = sA1 - c_last * p.mb1[b * 256 + t] + wd_last * p.b1[b * 256 + t];
        p.out[OUT_MGB1 + b * 256 + t] = sM1 - mc_last * p.mb1[b * 256 + t];
        p.out[OUT_B2P + b * 256 + t]  = sA2 - c_last * p.mb2[b * 256 + t] + wd_last * p.b2[b * 256 + t];
        p.out[OUT_MGB2 + b * 256 + t] = sM2 - mc_last * p.mb2[b * 256 + t];
    }
}

// ---------------------------------------------------------------------------
// Phase 4: score2 (32u) + U2 (64u) + V2 (64u) = 160
// ---------------------------------------------------------------------------
__global__ __launch_bounds__(256) void phase4_kernel(KParams p) {
    __shared__ float smem[4160];
    int u = blockIdx.x, t = threadIdx.x;
    float* ws = p.ws;
    if (u < 32) {
        int b = u >> 4; int l0 = (u & 15) * 8;
        score_unit(p, smem, t, b, l0, OFF_XQ, OFF_X2T, OFF_P1);
    } else {
        int w = u - 32; int mat = w >> 6; int r = w & 63;
        int tt = r >> 1, ct = r & 1;
        int bl0 = tt * 8, c0 = ct * 128, b = bl0 >> 7;
        float (*xs)[260] = (float (*)[260])smem;
        stage8(ws + OFF_XQ + bl0 * 256, xs, t);
        __syncthreads();
        int tok = t >> 5, q = t & 31;
        int c = c0 + 4 * q;
        const float* W = ws + (mat ? OFF_MW2T : OFF_W2T) + b * 65536 + c;
        const float* bias = (mat ? p.mb2 : p.b2) + b * 256 + c;
        float4 a = dot256(xs, tok, W, 256);
        float4 bb = *(const float4*)bias;
        a.x += bb.x; a.y += bb.y; a.z += bb.z; a.w += bb.w;
        *(float4*)(ws + (mat ? OFF_V2 : OFF_U2) + (bl0 + tok) * 256 + c) = a;
    }
}

// ---------------------------------------------------------------------------
// Phase 5: combine2 -> out ZQ2 (64u, chain 9)
// ---------------------------------------------------------------------------
__global__ __launch_bounds__(256) void phase5_kernel(KParams p) {
    __shared__ float smem[1056];
    int u = blockIdx.x, t = threadIdx.x;
    int tt = u >> 1, ct = u & 1;
    int b = tt >> 4, l0 = (tt & 15) * 8;
    combine_unit(p, smem, t, b, l0, ct * 128, OFF_P1, OFF_GZ2,
                 OFF_U2, OFF_V2, 0, p.out + OUT_ZQ2);
}

// ---------------------------------------------------------------------------
extern "C" void kernel_launch(void* const* d_in, const int* in_sizes, int n_in,
                              void* d_out, int out_size, void* d_ws, size_t ws_size,
                              hipStream_t stream) {
    KParams p;
    p.x   = (const float*)d_in[0];
    p.Wq  = (const float*)d_in[1];  p.bq  = (const float*)d_in[2];
    p.Wk  = (const float*)d_in[3];  p.bk  = (const float*)d_in[4];
    p.Wv  = (const float*)d_in[5];  p.bv  = (const float*)d_in[6];
    p.Wlr = (const float*)d_in[7];  p.blr = (const float*)d_in[8];
    p.Wm  = (const float*)d_in[9];  p.bm  = (const float*)d_in[10];
    p.Wd  = (const float*)d_in[11]; p.bd  = (const float*)d_in[12];
    p.W1  = (const float*)d_in[13]; p.b1  = (const float*)d_in[14];
    p.W2  = (const float*)d_in[15]; p.b2  = (const float*)d_in[16];
    p.mW1 = (const float*)d_in[17]; p.mb1 = (const float*)d_in[18];
    p.mW2 = (const float*)d_in[19]; p.mb2 = (const float*)d_in[20];
    p.out = (float*)d_out;
    p.ws  = (float*)d_ws;

    phase0_kernel<<<768, 256, 0, stream>>>(p);
    phase1_kernel<<<448, 256, 0, stream>>>(p);
    phase2_kernel<<<64, 256, 0, stream>>>(p);
    phase3_kernel<<<1090, 256, 0, stream>>>(p);
    phase4_kernel<<<160, 256, 0, stream>>>(p);
    phase5_kernel<<<64, 256, 0, stream>>>(p);
}